// Round 1
// baseline (317.110 us; speedup 1.0000x reference)
//
#include <hip/hip_runtime.h>
#include <math.h>

#define C 28   // channels == dim_head == rank
#define N 64   // tokens per window (8x8)

__global__ __launch_bounds__(256, 2)
void fa_fused(const float* __restrict__ x,
              const float* __restrict__ Wqk,   // [56][28]
              const float* __restrict__ Wv,    // [28][28]
              const float* __restrict__ Wout,  // [28][28]
              const float* __restrict__ bout,  // [28]
              const float* __restrict__ Wpcq,  // [28]
              const float* __restrict__ bpcq,  // [1]
              const float* __restrict__ Wpck,  // [28]
              const float* __restrict__ bpck,  // [1]
              const float* __restrict__ Wm1,   // [64]
              const float* __restrict__ Wm2a,  // [64][64]
              const float* __restrict__ Wm2b,  // [64]
              float* __restrict__ out)
{
    __shared__ float kbuf[4][N][C];
    __shared__ float vbuf[4][N][C];
    __shared__ float sgk[4][N];
    __shared__ float thb[4][N];

    const int wv = threadIdx.x >> 6;
    const int ln = threadIdx.x & 63;
    const int pid = blockIdx.x * 4 + wv;   // 0..8191
    const int win = pid >> 3;              // 0..1023
    const int Bi  = pid & 7;
    const int hw = win >> 5, ww = win & 31;
    const int b0 = ln >> 3, b1 = ln & 7;
    const size_t base = ((((size_t)Bi * 256) + (size_t)(hw * 8 + b0)) * 256
                         + (size_t)(ww * 8 + b1)) * C;

    // ---- load x row (28 floats, 112B-aligned) ----
    float xr[C];
    {
        const float4* p = (const float4*)(x + base);
        #pragma unroll
        for (int i = 0; i < 7; ++i) {
            float4 t = p[i];
            xr[4*i+0] = t.x; xr[4*i+1] = t.y; xr[4*i+2] = t.z; xr[4*i+3] = t.w;
        }
    }

    // ---- q projection (unrolled: q[] must stay in VGPRs) ----
    float q[C];
    #pragma unroll
    for (int d = 0; d < C; ++d) {
        float a0 = 0.f, a1 = 0.f;
        #pragma unroll
        for (int c = 0; c < C; c += 2) {
            a0 += Wqk[d*C + c]     * xr[c];
            a1 += Wqk[d*C + c + 1] * xr[c+1];
        }
        q[d] = a0 + a1;
    }
    // sig_q
    float sq;
    {
        float a0 = 0.f, a1 = 0.f;
        #pragma unroll
        for (int d = 0; d < C; d += 2) { a0 += q[d]*Wpcq[d]; a1 += q[d+1]*Wpcq[d+1]; }
        sq = a0 + a1 + bpcq[0];
    }

    // ---- k, v projections: rolled loop writing straight to LDS (code-size) ----
    {
        float ak_sig = 0.f;
        #pragma unroll 1
        for (int d = 0; d < C; ++d) {
            float k0 = 0.f, k1 = 0.f, v0 = 0.f, v1 = 0.f;
            #pragma unroll
            for (int c = 0; c < C; c += 2) {
                k0 += Wqk[(C+d)*C + c]     * xr[c];
                k1 += Wqk[(C+d)*C + c + 1] * xr[c+1];
                v0 += Wv[d*C + c]          * xr[c];
                v1 += Wv[d*C + c + 1]      * xr[c+1];
            }
            float kd = k0 + k1;
            kbuf[wv][ln][d] = kd;
            vbuf[wv][ln][d] = v0 + v1;
            ak_sig += kd * Wpck[d];
        }
        sgk[wv][ln] = ak_sig + bpck[0];
    }
    __syncthreads();

    // ---- sim row (raw), theta_i accumulation, Sigma scale, row max ----
    float sim[N];
    float th = 0.f;
    float m = -1e30f;
    const float* kw = &kbuf[wv][0][0];
    const float* vw = &vbuf[wv][0][0];
    #pragma unroll
    for (int j = 0; j < N; ++j) {
        const float4* kj = (const float4*)(kw + j*C);
        float a0 = 0.f, a1 = 0.f, a2 = 0.f, a3 = 0.f;
        #pragma unroll
        for (int c4 = 0; c4 < 7; ++c4) {
            float4 kk = kj[c4];
            a0 += q[4*c4+0] * kk.x;
            a1 += q[4*c4+1] * kk.y;
            a2 += q[4*c4+2] * kk.z;
            a3 += q[4*c4+3] * kk.w;
        }
        float sraw = (a0 + a1) + (a2 + a3);
        // diagonal removed only for theta
        th += (j == ln) ? 0.f : sraw * Wm1[j];
        float ss = sraw * sq * sgk[wv][j];
        sim[j] = ss;
        m = fmaxf(m, ss);
    }
    thb[wv][ln] = th;
    __syncthreads();

    // ---- MLP2: t = LeakyReLU(theta @ Wm2a^T, 0.1); theta_s = t @ Wm2b^T ----
    float tP;
    {
        const float* thw = &thb[wv][0];
        const float* wrow = Wm2a + ln * N;   // per-lane row, L1-cached
        float a0 = 0.f, a1 = 0.f, a2 = 0.f, a3 = 0.f;
        #pragma unroll 4
        for (int i = 0; i < N; i += 4) {
            a0 += thw[i]   * wrow[i];
            a1 += thw[i+1] * wrow[i+1];
            a2 += thw[i+2] * wrow[i+2];
            a3 += thw[i+3] * wrow[i+3];
        }
        float t = (a0 + a1) + (a2 + a3);
        t = (t >= 0.f) ? t : 0.1f * t;
        tP = t * Wm2b[ln];
    }
    // butterfly sum across the 64 lanes -> scalar theta in every lane
    float theta = tP;
    #pragma unroll
    for (int off = 32; off > 0; off >>= 1)
        theta += __shfl_xor(theta, off, 64);

    // ---- fused softmax (full row) + threshold mask + attn @ v (unnormalized) ----
    float o[C];
    #pragma unroll
    for (int d = 0; d < C; ++d) o[d] = 0.f;
    float Z = 0.f;
    #pragma unroll
    for (int j = 0; j < N; ++j) {
        float e = __expf(sim[j] - m);
        Z += e;
        float a = (sim[j] > theta) ? e : 0.f;
        const float4* vj = (const float4*)(vw + j*C);
        #pragma unroll
        for (int c4 = 0; c4 < 7; ++c4) {
            float4 vvv = vj[c4];
            o[4*c4+0] += a * vvv.x;
            o[4*c4+1] += a * vvv.y;
            o[4*c4+2] += a * vvv.z;
            o[4*c4+3] += a * vvv.w;
        }
    }
    {
        float rz = 1.0f / Z;
        #pragma unroll
        for (int d = 0; d < C; ++d) o[d] *= rz;
    }

    // ---- output projection + bias, rolled (scalar weights), scalar stores ----
    float* yp = out + base;
    #pragma unroll 1
    for (int e = 0; e < C; ++e) {
        float a0 = 0.f, a1 = 0.f;
        #pragma unroll
        for (int d = 0; d < C; d += 2) {
            a0 += Wout[e*C + d]     * o[d];
            a1 += Wout[e*C + d + 1] * o[d+1];
        }
        yp[e] = (a0 + a1) + bout[e];
    }
}

extern "C" void kernel_launch(void* const* d_in, const int* in_sizes, int n_in,
                              void* d_out, int out_size, void* d_ws, size_t ws_size,
                              hipStream_t stream) {
    const float* x     = (const float*)d_in[0];
    const float* W_qk  = (const float*)d_in[1];
    const float* W_v   = (const float*)d_in[2];
    const float* W_out = (const float*)d_in[3];
    const float* b_out = (const float*)d_in[4];
    const float* W_pcq = (const float*)d_in[5];
    const float* b_pcq = (const float*)d_in[6];
    const float* W_pck = (const float*)d_in[7];
    const float* b_pck = (const float*)d_in[8];
    const float* W_m1  = (const float*)d_in[9];
    const float* W_m2a = (const float*)d_in[10];
    const float* W_m2b = (const float*)d_in[11];
    float* y = (float*)d_out;

    // 8192 problems (1024 windows x B=8), 4 problems per 256-thread block
    dim3 grid(2048), block(256);
    hipLaunchKernelGGL(fa_fused, grid, block, 0, stream,
                       x, W_qk, W_v, W_out, b_out, W_pcq, b_pcq,
                       W_pck, b_pck, W_m1, W_m2a, W_m2b, y);
}